// Round 3
// baseline (1092.458 us; speedup 1.0000x reference)
//
#include <hip/hip_runtime.h>

// Longformer sliding-chunks no-overlap attention, fused single kernel.
// b=2, s=8192, h=8, d=64, W=256, c=32. Window = [prev, self, next] chunks,
// ZERO-padded at boundaries (padded scores are exactly 0 and participate in
// the softmax denominator, matching the reference).
//
// d_out layout: [output (b,s,h,64) = 8388608 f32][attention (b,s,h,768) = 100663296 f32]
//
// Mapping: lane owns keys (lane*4 + jj), jj=0..3, per chunk e -> row's 12
// probs are 3 contiguous float4 -> dwordx4 attention stores + float4 P-staging.
// K tile in LDS is XOR-swizzled (granule ^= (key>>2)&15) so the 4-rows-per-lane
// b128 reads spread uniformly over banks (8 accesses/bank = b128 minimum).

#define SEQ  8192
#define NH   8
#define DM   64
#define WIN  256
#define NC   32
#define TILE 32   // q rows per block
#define RW   8    // q rows per wave (4 waves)

typedef float fx4 __attribute__((ext_vector_type(4)));  // native vector for nontemporal builtin

__global__ __launch_bounds__(256, 2)
void wattn_fused(const float* __restrict__ qg,
                 const float* __restrict__ kg,
                 const float* __restrict__ vg,
                 float* __restrict__ outg,
                 float* __restrict__ attng)
{
    __shared__ float lds_q[TILE * DM];   // 8 KB: q tile [32][64]
    __shared__ float lds_buf[WIN * DM];  // 64 KB: phase1 K-chunk (swizzled)
                                         // phase3: V-half [128][64] @0 + P [32][256] @8192

    const int t    = threadIdx.x;
    const int lane = t & 63;
    const int w    = t >> 6;   // wave id 0..3

    int gid = blockIdx.x;
    const int tile = gid & 7;  gid >>= 3;
    const int hh   = gid & 7;  gid >>= 3;
    const int cc   = gid & 31; gid >>= 5;
    const int bb   = gid;

    const int row0 = cc * WIN + tile * TILE;   // first seq row of this tile

    // ---------------- stage Q tile (coalesced float4) ----------------
    #pragma unroll
    for (int i = 0; i < 2; ++i) {
        int idx = t + (i << 8);          // 0..511
        int r   = idx >> 4;              // 0..31
        int f4  = idx & 15;
        const float4* src = reinterpret_cast<const float4*>(
            qg + (((size_t)bb * SEQ + row0 + r) * NH + hh) * DM) + f4;
        reinterpret_cast<float4*>(lds_q)[(r << 4) + f4] = *src;
    }

    // scores: 8 rows x 12 window slots; slot e*4+jj = window pos e*256 + lane*4 + jj
    float sc[RW][12];
    #pragma unroll
    for (int r = 0; r < RW; ++r)
        #pragma unroll
        for (int j = 0; j < 12; ++j) sc[r][j] = 0.f;

    // ---------------- phase 1: QK^T over 3 key chunks ----------------
    for (int e = 0; e < 3; ++e) {
        __syncthreads();   // prev compute done (e=0: covers Q staging too)

        const int  cs    = cc + e - 1;
        const bool valid = ((unsigned)cs) < NC;
        const float* kbase = kg + (((size_t)bb * SEQ + (size_t)cs * WIN) * NH + hh) * DM;

        // stage K chunk [256][64], XOR-swizzled float4 granules
        #pragma unroll
        for (int i = 0; i < 16; ++i) {
            int idx = t + (i << 8);       // 0..4095
            int key = idx >> 4;           // 0..255
            int f4  = idx & 15;
            float4 val = make_float4(0.f, 0.f, 0.f, 0.f);
            if (valid)
                val = *(reinterpret_cast<const float4*>(kbase + (size_t)key * NH * DM) + f4);
            int f4s = f4 ^ ((key >> 2) & 15);
            reinterpret_cast<float4*>(lds_buf)[(key << 4) + f4s] = val;
        }
        __syncthreads();

        // compute: lane's keys lane*4+jj; q reads are wave-uniform broadcasts
        #pragma unroll 4
        for (int f4 = 0; f4 < 16; ++f4) {
            float4 kv[4];
            #pragma unroll
            for (int jj = 0; jj < 4; ++jj) {
                int key = (lane << 2) | jj;
                kv[jj] = reinterpret_cast<const float4*>(lds_buf)[(key << 4) + (f4 ^ (lane & 15))];
            }
            #pragma unroll
            for (int r = 0; r < RW; ++r) {
                float4 qv = reinterpret_cast<const float4*>(lds_q)[((w * RW + r) << 4) + f4];
                #pragma unroll
                for (int jj = 0; jj < 4; ++jj) {
                    sc[r][(e << 2) + jj] += qv.x * kv[jj].x + qv.y * kv[jj].y
                                          + qv.z * kv[jj].z + qv.w * kv[jj].w;
                }
            }
        }
    }

    // ---------------- phase 2: softmax over 768 + attention write ----------------
    #pragma unroll
    for (int r = 0; r < RW; ++r) {
        float m = sc[r][0];
        #pragma unroll
        for (int j = 1; j < 12; ++j) m = fmaxf(m, sc[r][j]);
        #pragma unroll
        for (int off = 32; off; off >>= 1) m = fmaxf(m, __shfl_xor(m, off, 64));

        float sum = 0.f;
        #pragma unroll
        for (int j = 0; j < 12; ++j) {
            float p = __expf(sc[r][j] - m);
            sc[r][j] = p;
            sum += p;
        }
        #pragma unroll
        for (int off = 32; off; off >>= 1) sum += __shfl_xor(sum, off, 64);

        float inv = 1.f / sum;
        fx4* ab4 = reinterpret_cast<fx4*>(
            attng + (((size_t)bb * SEQ + row0 + w * RW + r) * NH + hh) * (3 * WIN));
        #pragma unroll
        for (int e2 = 0; e2 < 3; ++e2) {
            fx4 pv;
            pv.x = sc[r][(e2 << 2) + 0] * inv;
            pv.y = sc[r][(e2 << 2) + 1] * inv;
            pv.z = sc[r][(e2 << 2) + 2] * inv;
            pv.w = sc[r][(e2 << 2) + 3] * inv;
            sc[r][(e2 << 2) + 0] = pv.x;
            sc[r][(e2 << 2) + 1] = pv.y;
            sc[r][(e2 << 2) + 2] = pv.z;
            sc[r][(e2 << 2) + 3] = pv.w;
            // window pos e2*256 + lane*4 -> float4 index e2*64 + lane (streaming store)
            __builtin_nontemporal_store(pv, ab4 + (e2 << 6) + lane);
        }
    }

    // ---------------- phase 3: PV over 3 chunks x 2 V-halves ----------------
    float acc[RW];
    #pragma unroll
    for (int r = 0; r < RW; ++r) acc[r] = 0.f;

    float* lds_p = lds_buf + 8192;   // [32][256] probs for current chunk e

    for (int e = 0; e < 3; ++e) {
        const int  cs    = cc + e - 1;
        const bool valid = ((unsigned)cs) < NC;

        __syncthreads();   // previous reads of lds_buf/lds_p done

        // stage P for this chunk: row-> [32][256], one float4 per (row)
        #pragma unroll
        for (int r = 0; r < RW; ++r) {
            int row = w * RW + r;
            float4 pv = make_float4(sc[r][(e << 2) + 0], sc[r][(e << 2) + 1],
                                    sc[r][(e << 2) + 2], sc[r][(e << 2) + 3]);
            reinterpret_cast<float4*>(lds_p)[(row << 6) + lane] = pv;
        }

        for (int half = 0; half < 2; ++half) {
            if (half == 1) __syncthreads();   // half0 compute reads done

            // stage V half [128][64], plain layout (PV reads are bank-clean)
            const float* vbase = vg +
                (((size_t)bb * SEQ + (size_t)cs * WIN + half * 128) * NH + hh) * DM;
            #pragma unroll
            for (int i = 0; i < 8; ++i) {
                int idx = t + (i << 8);      // 0..2047
                int key = idx >> 4;          // 0..127
                int f4  = idx & 15;
                float4 val = make_float4(0.f, 0.f, 0.f, 0.f);
                if (valid)
                    val = *(reinterpret_cast<const float4*>(vbase + (size_t)key * NH * DM) + f4);
                reinterpret_cast<float4*>(lds_buf)[(key << 4) + f4] = val;
            }
            __syncthreads();

            // compute: lane owns output dim (=lane); p4 reads are broadcasts
            #pragma unroll 4
            for (int k = 0; k < 128; k += 4) {
                float vv[4];
                #pragma unroll
                for (int i = 0; i < 4; ++i) vv[i] = lds_buf[((k + i) << 6) + lane];
                #pragma unroll
                for (int r = 0; r < RW; ++r) {
                    const float4 p4 = *reinterpret_cast<const float4*>(
                        &lds_p[((w * RW + r) << 8) + (half << 7) + k]);
                    acc[r] += p4.x * vv[0] + p4.y * vv[1] + p4.z * vv[2] + p4.w * vv[3];
                }
            }
        }
    }

    // ---------------- write output ----------------
    #pragma unroll
    for (int r = 0; r < RW; ++r) {
        outg[(((size_t)bb * SEQ + row0 + w * RW + r) * NH + hh) * DM + lane] = acc[r];
    }
}

extern "C" void kernel_launch(void* const* d_in, const int* in_sizes, int n_in,
                              void* d_out, int out_size, void* d_ws, size_t ws_size,
                              hipStream_t stream) {
    const float* q = (const float*)d_in[0];
    const float* k = (const float*)d_in[1];
    const float* v = (const float*)d_in[2];

    float* out  = (float*)d_out;                              // (b,s,h,64)
    float* attn = (float*)d_out + (size_t)2 * SEQ * NH * DM;  // (b,s,h,768)

    // blocks: b * c * h * (W/TILE) = 2*32*8*8 = 4096
    dim3 grid(2 * NC * NH * (WIN / TILE));
    dim3 block(256);
    wattn_fused<<<grid, block, 0, stream>>>(q, k, v, out, attn);
}

// Round 4
// 669.881 us; speedup vs baseline: 1.6308x; 1.6308x over previous
//
#include <hip/hip_runtime.h>

// Longformer sliding-chunks no-overlap attention, fused, MFMA-based.
// b=2, s=8192, h=8, d=64, W=256, c=32. Window = [prev,self,next] chunks,
// zero-padded at boundaries (padded scores exactly 0, kept in softmax denom).
//
// Structure per block (bb, cc, hh, 32-row q-tile), 4 waves:
//   wave w owns key slice [w*64, w*64+64) of each chunk.
//   QK^T: mfma_f32_16x16x32_bf16, Markidis 3-term split (QhKh+QhKl+QlKh),
//         A=Q and B=K fragments loaded DIRECTLY from global (L1/L2), no barriers.
//   softmax: row partials in C-layout (col=lane&15, row=(lane>>4)*4+reg),
//         16-lane shfl reduce + cross-wave LDS reduce (2 barriers).
//   PV:   plain bf16 MFMA. P staged to wave-private LDS (layout transpose,
//         XOR-swizzled); V staged transposed to k-major-packed bf16.
//   epilogue: cross-wave fp32 C reduction through LDS.
//
// d_out layout: [output (b,s,h,64)][attention (b,s,h,768)], both f32.

#define SEQ  8192
#define NH   8
#define DM   64
#define WIN  256
#define NC   32

typedef float  f32x4  __attribute__((ext_vector_type(4)));
typedef short  bf16x8 __attribute__((ext_vector_type(8)));

__device__ __forceinline__ unsigned short bf16_rne(float x) {
    unsigned u = __builtin_bit_cast(unsigned, x);
    u += 0x7FFFu + ((u >> 16) & 1u);
    return (unsigned short)(u >> 16);
}
__device__ __forceinline__ float bf16_f32(unsigned short h) {
    unsigned u = ((unsigned)h) << 16;
    return __builtin_bit_cast(float, u);
}

__global__ __launch_bounds__(256, 2)
void wattn_mfma(const float* __restrict__ qg, const float* __restrict__ kg,
                const float* __restrict__ vg, float* __restrict__ outg,
                float* __restrict__ attng)
{
    // LDS map (bytes):
    //   [0, 32768)      vt: per-wave transposed V, k-major packed bf16
    //                   elem = dt*1024 + (kk>>3)*128 + (d&15)*8 + (kk&7)
    //   [32768, 49152)  P:  per-wave probs bf16 [32][64], granule XOR row&7
    //   [49152, 50176)  smax/ssum [32][4] f32 each
    //   [0, 34816)      (epilogue overlay) C-scratch [4][32][68] f32
    __shared__ __align__(16) char lds[50176];

    const int t    = threadIdx.x;
    const int lane = t & 63;
    const int w    = t >> 6;
    const int a    = lane & 15;
    const int g4   = lane >> 4;

    unsigned short* vtw = (unsigned short*)(lds)         + w * 4096;
    unsigned short* plw = (unsigned short*)(lds + 32768) + w * 2048;
    float* smax = (float*)(lds + 49152);   // [32][4]
    float* ssum = smax + 128;              // [32][4]
    float* csc  = (float*)lds;             // [4][32][68]

    int gid = blockIdx.x;
    gid = (gid & 7) * 512 + (gid >> 3);    // XCD swizzle, 4096 = 8*512 (bijective)
    const int tile = gid & 7;  gid >>= 3;
    const int hh   = gid & 7;  gid >>= 3;
    const int cc   = gid & 31; gid >>= 5;
    const int bb   = gid;
    const int row0 = cc * WIN + tile * 32;

    // ---------------- Q fragments (global -> regs, hi/lo split) ----------------
    bf16x8 qh[2][2], ql[2][2];
    #pragma unroll
    for (int rt = 0; rt < 2; ++rt)
      #pragma unroll
      for (int ks = 0; ks < 2; ++ks) {
        const float* qp = qg + (((size_t)bb * SEQ + row0 + rt*16 + a) * NH + hh) * DM
                             + ks*32 + g4*8;
        f32x4 t0 = *(const f32x4*)qp;
        f32x4 t1 = *(const f32x4*)(qp + 4);
        float f[8];
        #pragma unroll
        for (int i = 0; i < 4; ++i) { f[i] = t0[i]; f[4+i] = t1[i]; }
        #pragma unroll
        for (int i = 0; i < 8; ++i) {
            unsigned short h = bf16_rne(f[i]);
            qh[rt][ks][i] = (short)h;
            ql[rt][ks][i] = (short)bf16_rne(f[i] - bf16_f32(h));
        }
      }

    // ---------------- QK^T (no LDS, no barriers) ----------------
    f32x4 acc[3][2][4];
    #pragma unroll
    for (int e = 0; e < 3; ++e)
      #pragma unroll
      for (int rt = 0; rt < 2; ++rt)
        #pragma unroll
        for (int ct = 0; ct < 4; ++ct)
            acc[e][rt][ct] = (f32x4){0.f, 0.f, 0.f, 0.f};

    #pragma unroll
    for (int e = 0; e < 3; ++e) {
        const int cs = cc + e - 1;
        if ((unsigned)cs < NC) {
            #pragma unroll
            for (int ct = 0; ct < 4; ++ct) {
                const float* kp = kg + (((size_t)bb * SEQ + cs*WIN + w*64 + ct*16 + a) * NH + hh) * DM;
                #pragma unroll
                for (int ks = 0; ks < 2; ++ks) {
                    f32x4 t0 = *(const f32x4*)(kp + ks*32 + g4*8);
                    f32x4 t1 = *(const f32x4*)(kp + ks*32 + g4*8 + 4);
                    float f[8];
                    #pragma unroll
                    for (int i = 0; i < 4; ++i) { f[i] = t0[i]; f[4+i] = t1[i]; }
                    bf16x8 kh, kl;
                    #pragma unroll
                    for (int i = 0; i < 8; ++i) {
                        unsigned short h = bf16_rne(f[i]);
                        kh[i] = (short)h;
                        kl[i] = (short)bf16_rne(f[i] - bf16_f32(h));
                    }
                    #pragma unroll
                    for (int rt = 0; rt < 2; ++rt) {
                        acc[e][rt][ct] = __builtin_amdgcn_mfma_f32_16x16x32_bf16(qh[rt][ks], kh, acc[e][rt][ct], 0, 0, 0);
                        acc[e][rt][ct] = __builtin_amdgcn_mfma_f32_16x16x32_bf16(qh[rt][ks], kl, acc[e][rt][ct], 0, 0, 0);
                        acc[e][rt][ct] = __builtin_amdgcn_mfma_f32_16x16x32_bf16(ql[rt][ks], kh, acc[e][rt][ct], 0, 0, 0);
                    }
                }
            }
        }
    }

    // ---------------- softmax over 768 (C-layout rows) ----------------
    // row of slot (rt,reg) = rt*16 + g4*4 + reg; cols = e*256 + w*64 + ct*16 + a
    float M[2][4], INV[2][4];
    #pragma unroll
    for (int rt = 0; rt < 2; ++rt)
      #pragma unroll
      for (int reg = 0; reg < 4; ++reg) {
        float mm = -3.4e38f;
        #pragma unroll
        for (int e = 0; e < 3; ++e)
          #pragma unroll
          for (int ct = 0; ct < 4; ++ct)
            mm = fmaxf(mm, acc[e][rt][ct][reg]);
        mm = fmaxf(mm, __shfl_xor(mm, 1));
        mm = fmaxf(mm, __shfl_xor(mm, 2));
        mm = fmaxf(mm, __shfl_xor(mm, 4));
        mm = fmaxf(mm, __shfl_xor(mm, 8));
        if (a == 0) smax[(rt*16 + g4*4 + reg)*4 + w] = mm;
      }
    __syncthreads();
    #pragma unroll
    for (int rt = 0; rt < 2; ++rt)
      #pragma unroll
      for (int reg = 0; reg < 4; ++reg) {
        const float* sp = smax + (rt*16 + g4*4 + reg)*4;
        float mm = fmaxf(fmaxf(sp[0], sp[1]), fmaxf(sp[2], sp[3]));
        M[rt][reg] = mm;
        float s = 0.f;
        #pragma unroll
        for (int e = 0; e < 3; ++e)
          #pragma unroll
          for (int ct = 0; ct < 4; ++ct) {
            float p = __expf(acc[e][rt][ct][reg] - mm);
            acc[e][rt][ct][reg] = p;
            s += p;
          }
        s += __shfl_xor(s, 1);
        s += __shfl_xor(s, 2);
        s += __shfl_xor(s, 4);
        s += __shfl_xor(s, 8);
        if (a == 0) ssum[(rt*16 + g4*4 + reg)*4 + w] = s;
      }
    __syncthreads();
    #pragma unroll
    for (int rt = 0; rt < 2; ++rt)
      #pragma unroll
      for (int reg = 0; reg < 4; ++reg) {
        const float* sp = ssum + (rt*16 + g4*4 + reg)*4;
        INV[rt][reg] = 1.0f / (sp[0] + sp[1] + sp[2] + sp[3]);
      }

    // scale to probs + attention store (streaming)
    #pragma unroll
    for (int rt = 0; rt < 2; ++rt)
      #pragma unroll
      for (int reg = 0; reg < 4; ++reg) {
        const float iv = INV[rt][reg];
        float* ab = attng + (((size_t)bb * SEQ + row0 + rt*16 + g4*4 + reg) * NH + hh) * 768
                          + w*64 + a;
        #pragma unroll
        for (int e = 0; e < 3; ++e)
          #pragma unroll
          for (int ct = 0; ct < 4; ++ct) {
            float p = acc[e][rt][ct][reg] * iv;
            acc[e][rt][ct][reg] = p;
            __builtin_nontemporal_store(p, ab + e*256 + ct*16);
          }
      }

    // ---------------- PV (bf16 MFMA, wave-private LDS) ----------------
    f32x4 acc2[2][4];
    #pragma unroll
    for (int rt = 0; rt < 2; ++rt)
      #pragma unroll
      for (int dt = 0; dt < 4; ++dt)
        acc2[rt][dt] = (f32x4){0.f, 0.f, 0.f, 0.f};

    #pragma unroll
    for (int e = 0; e < 3; ++e) {
        const int cs = cc + e - 1;
        if ((unsigned)cs < NC) {          // block-uniform branch
            __syncthreads();              // WAR: prev chunk's frag reads done
            // stage V transposed: k-major packed bf16
            #pragma unroll
            for (int i = 0; i < 16; ++i) {
                const int kk = i*4 + g4;
                const float* vp = vg + (((size_t)bb * SEQ + cs*WIN + w*64 + kk) * NH + hh) * DM
                                     + a*4;
                f32x4 v4 = *(const f32x4*)vp;
                #pragma unroll
                for (int j = 0; j < 4; ++j) {
                    const int d = a*4 + j;
                    vtw[(d>>4)*1024 + (kk>>3)*128 + (d&15)*8 + (kk&7)] = bf16_rne(v4[j]);
                }
            }
            // stage P (C-layout -> A-layout, XOR swizzle by row&7)
            #pragma unroll
            for (int rt = 0; rt < 2; ++rt)
              #pragma unroll
              for (int reg = 0; reg < 4; ++reg) {
                const int prow = rt*16 + g4*4 + reg;
                #pragma unroll
                for (int ct = 0; ct < 4; ++ct) {
                    const int key = ct*16 + a;
                    plw[prow*64 + (((key>>3) ^ (prow&7)) << 3) + (key&7)] =
                        bf16_rne(acc[e][rt][ct][reg]);
                }
              }
            __syncthreads();
            // fragments + MFMA
            #pragma unroll
            for (int ks = 0; ks < 2; ++ks) {
                bf16x8 pa[2], vb[4];
                #pragma unroll
                for (int rt = 0; rt < 2; ++rt) {
                    const int prow = rt*16 + a;
                    pa[rt] = *(const bf16x8*)(plw + prow*64 + ((((ks<<2) + g4) ^ (prow&7)) << 3));
                }
                #pragma unroll
                for (int dt = 0; dt < 4; ++dt)
                    vb[dt] = *(const bf16x8*)(vtw + dt*1024 + ((ks<<2) + g4)*128 + a*8);
                #pragma unroll
                for (int rt = 0; rt < 2; ++rt)
                  #pragma unroll
                  for (int dt = 0; dt < 4; ++dt)
                    acc2[rt][dt] = __builtin_amdgcn_mfma_f32_16x16x32_bf16(pa[rt], vb[dt], acc2[rt][dt], 0, 0, 0);
            }
        }
    }

    // ---------------- cross-wave C reduction + output ----------------
    __syncthreads();   // all PV frag reads done before overlaying vt/P with C
    #pragma unroll
    for (int rt = 0; rt < 2; ++rt)
      #pragma unroll
      for (int dt = 0; dt < 4; ++dt)
        #pragma unroll
        for (int reg = 0; reg < 4; ++reg)
          csc[w*2176 + (rt*16 + g4*4 + reg)*68 + dt*16 + a] = acc2[rt][dt][reg];
    __syncthreads();
    #pragma unroll
    for (int r = 0; r < 8; ++r) {
        const int row = w*8 + r;
        float s = csc[          row*68 + lane] + csc[  2176 + row*68 + lane]
                + csc[2*2176 + row*68 + lane] + csc[3*2176 + row*68 + lane];
        __builtin_nontemporal_store(
            s, outg + (((size_t)bb * SEQ + row0 + row) * NH + hh) * DM + lane);
    }
}

extern "C" void kernel_launch(void* const* d_in, const int* in_sizes, int n_in,
                              void* d_out, int out_size, void* d_ws, size_t ws_size,
                              hipStream_t stream) {
    const float* q = (const float*)d_in[0];
    const float* k = (const float*)d_in[1];
    const float* v = (const float*)d_in[2];

    float* out  = (float*)d_out;                              // (b,s,h,64)
    float* attn = (float*)d_out + (size_t)2 * SEQ * NH * DM;  // (b,s,h,768)

    dim3 grid(2 * NC * NH * (WIN / 32));   // 4096
    dim3 block(256);
    wattn_mfma<<<grid, block, 0, stream>>>(q, k, v, out, attn);
}

// Round 5
// 638.795 us; speedup vs baseline: 1.7102x; 1.0487x over previous
//
#include <hip/hip_runtime.h>

// Longformer sliding-chunks no-overlap attention. b=2, s=8192, h=8, d=64, W=256.
// Two-kernel scheme (if ws_size >= 50.3MB, else fallback to proven R4 kernel):
//   prep:  K -> Kh,Kl bf16 (Markidis split, converted ONCE, layout (b,s,h,d));
//          V -> Vt bf16 transposed to (b,h,d,s).
//   main:  per (bb,cc,hh,32-row tile), 4 waves, wave owns 64-key slice.
//     QK:  S^T = K*Q^T via mfma_16x16x32_bf16 (KhQh+KhQl+KlQh), frags from global.
//     SM:  rows on lane&15 -> 2-step shfl + cross-wave LDS reduce.
//     att: b128 nontemporal stores (lane holds 4 consecutive window cols).
//     PV:  O^T = V^T*P^T. V^T frags DIRECT from global (Vt). P^T via wave-private
//          bf16 LDS [32][72] (aligned b64 writes, b128 frag reads, no barriers).
//     epi: cross-wave fp32 reduce through LDS (b128 writes).
//
// d_out: [output (b,s,h,64)][attention (b,s,h,768)], both f32.

#define SEQ  8192
#define NH   8
#define DM   64
#define WIN  256
#define NC   32

typedef float  f32x4  __attribute__((ext_vector_type(4)));
typedef short  bf16x8 __attribute__((ext_vector_type(8)));
typedef short  bf16x4 __attribute__((ext_vector_type(4)));
typedef unsigned short u16;

__device__ __forceinline__ u16 bf16_rne(float x) {
    unsigned u = __builtin_bit_cast(unsigned, x);
    u += 0x7FFFu + ((u >> 16) & 1u);
    return (u16)(u >> 16);
}
__device__ __forceinline__ float bf16_f32(u16 h) {
    unsigned u = ((unsigned)h) << 16;
    return __builtin_bit_cast(float, u);
}

// ---------------------------------------------------------------- prep kernel
__global__ __launch_bounds__(256)
void wattn_prep(const float* __restrict__ kg, const float* __restrict__ vg,
                u16* __restrict__ khp, u16* __restrict__ klp, u16* __restrict__ vtp)
{
    __shared__ float tile[64 * 68];   // V transpose staging (padded)
    const int bid = blockIdx.x;
    const int t   = threadIdx.x;

    if (bid < 4096) {
        // K -> hi/lo bf16, flat convert (8 elems/thread)
        const size_t base = (size_t)bid * 2048 + t * 8;
        f32x4 a0 = *(const f32x4*)(kg + base);
        f32x4 a1 = *(const f32x4*)(kg + base + 4);
        bf16x8 h, l;
        #pragma unroll
        for (int i = 0; i < 8; ++i) {
            float f = (i < 4) ? a0[i] : a1[i - 4];
            u16 hh = bf16_rne(f);
            h[i] = (short)hh;
            l[i] = (short)bf16_rne(f - bf16_f32(hh));
        }
        *(bf16x8*)(khp + base) = h;
        *(bf16x8*)(klp + base) = l;
    } else {
        // V transpose: (b,s,h,d) f32 -> (b,h,d,s) bf16, 64x64 tile
        const int vid = bid - 4096;
        const int st  = vid & 127;
        const int hh  = (vid >> 7) & 7;
        const int bb  = vid >> 10;
        const int s0  = st * 64;

        const int r  = t >> 2;
        const int dg = (t & 3) * 16;
        const float* vp = vg + (((size_t)bb * SEQ + s0 + r) * NH + hh) * DM + dg;
        #pragma unroll
        for (int i = 0; i < 4; ++i)
            *(f32x4*)&tile[r * 68 + dg + 4 * i] = *(const f32x4*)(vp + 4 * i);
        __syncthreads();

        const int d  = t >> 2;
        const int sg = (t & 3) * 16;
        u16* op = vtp + (((size_t)bb * NH + hh) * DM + d) * SEQ + s0 + sg;
        bf16x8 o0, o1;
        #pragma unroll
        for (int j = 0; j < 8; ++j) o0[j] = (short)bf16_rne(tile[(sg + j) * 68 + d]);
        #pragma unroll
        for (int j = 0; j < 8; ++j) o1[j] = (short)bf16_rne(tile[(sg + 8 + j) * 68 + d]);
        *(bf16x8*)op       = o0;
        *(bf16x8*)(op + 8) = o1;
    }
}

// ---------------------------------------------------------------- main kernel
__global__ __launch_bounds__(256, 2)
void wattn_mfma2(const float* __restrict__ qg, const u16* __restrict__ khp,
                 const u16* __restrict__ klp, const u16* __restrict__ vtp,
                 float* __restrict__ outg, float* __restrict__ attng)
{
    // LDS: [0,34816) csc f32[4][32][68] (epilogue) overlaying per-wave P
    //      pw (per wave) = u16[32][72] @ w*4608 bytes
    //      [34816,35328) smax f32[32][4]; [35328,35840) ssum
    __shared__ __align__(16) char lds[35840];

    const int t    = threadIdx.x;
    const int lane = t & 63;
    const int w    = t >> 6;
    const int a    = lane & 15;
    const int g4   = lane >> 4;

    u16*   pw   = (u16*)(lds) + w * 2304;   // 32*72 u16 per wave
    float* csc  = (float*)lds;              // [4][32][68]
    float* smax = (float*)(lds + 34816);    // [32][4]
    float* ssum = smax + 128;

    int gid = blockIdx.x;
    gid = (gid & 7) * 512 + (gid >> 3);     // XCD swizzle (bijective, 4096=8*512)
    const int tile = gid & 7;  gid >>= 3;
    const int hh   = gid & 7;  gid >>= 3;
    const int cc   = gid & 31; gid >>= 5;
    const int bb   = gid;
    const int row0 = cc * WIN + tile * 32;

    // ---- Q^T B-fragments (hi/lo split in-kernel: only 32 rows/block) ----
    bf16x8 qh[2][2], ql[2][2];
    #pragma unroll
    for (int rt = 0; rt < 2; ++rt)
      #pragma unroll
      for (int ks = 0; ks < 2; ++ks) {
        const float* qp = qg + (((size_t)bb * SEQ + row0 + rt*16 + a) * NH + hh) * DM
                             + ks*32 + g4*8;
        f32x4 t0 = *(const f32x4*)qp;
        f32x4 t1 = *(const f32x4*)(qp + 4);
        #pragma unroll
        for (int i = 0; i < 8; ++i) {
            float f = (i < 4) ? t0[i] : t1[i - 4];
            u16 hv = bf16_rne(f);
            qh[rt][ks][i] = (short)hv;
            ql[rt][ks][i] = (short)bf16_rne(f - bf16_f32(hv));
        }
      }

    // ---- QK^T as S^T = K*Q^T: acc[e][ct][rt], (key=ct*16+g4*4+reg, row=rt*16+a)
    f32x4 acc[3][4][2];
    #pragma unroll
    for (int e = 0; e < 3; ++e)
      #pragma unroll
      for (int ct = 0; ct < 4; ++ct)
        #pragma unroll
        for (int rt = 0; rt < 2; ++rt)
            acc[e][ct][rt] = (f32x4){0.f, 0.f, 0.f, 0.f};

    #pragma unroll
    for (int e = 0; e < 3; ++e) {
        const int cs = cc + e - 1;
        if ((unsigned)cs < NC) {
            #pragma unroll
            for (int ct = 0; ct < 4; ++ct) {
                const size_t koff = (((size_t)bb * SEQ + cs*WIN + w*64 + ct*16 + a) * NH + hh) * DM
                                  + g4*8;
                #pragma unroll
                for (int ks = 0; ks < 2; ++ks) {
                    bf16x8 kh = *(const bf16x8*)(khp + koff + ks*32);
                    bf16x8 kl = *(const bf16x8*)(klp + koff + ks*32);
                    #pragma unroll
                    for (int rt = 0; rt < 2; ++rt) {
                        acc[e][ct][rt] = __builtin_amdgcn_mfma_f32_16x16x32_bf16(kh, qh[rt][ks], acc[e][ct][rt], 0, 0, 0);
                        acc[e][ct][rt] = __builtin_amdgcn_mfma_f32_16x16x32_bf16(kh, ql[rt][ks], acc[e][ct][rt], 0, 0, 0);
                        acc[e][ct][rt] = __builtin_amdgcn_mfma_f32_16x16x32_bf16(kl, qh[rt][ks], acc[e][ct][rt], 0, 0, 0);
                    }
                }
            }
        }
    }

    // ---- softmax over 768 (row = rt*16 + a; lane's 48 values all same row) ----
    float M[2], INV[2];
    #pragma unroll
    for (int rt = 0; rt < 2; ++rt) {
        float mm = 0.f;   // padded slots contribute score 0
        #pragma unroll
        for (int e = 0; e < 3; ++e)
          #pragma unroll
          for (int ct = 0; ct < 4; ++ct)
            #pragma unroll
            for (int reg = 0; reg < 4; ++reg)
              mm = fmaxf(mm, acc[e][ct][rt][reg]);
        mm = fmaxf(mm, __shfl_xor(mm, 16));
        mm = fmaxf(mm, __shfl_xor(mm, 32));
        if (g4 == 0) smax[(rt*16 + a)*4 + w] = mm;
    }
    __syncthreads();
    #pragma unroll
    for (int rt = 0; rt < 2; ++rt) {
        const float* sp = smax + (rt*16 + a)*4;
        float mm = fmaxf(fmaxf(sp[0], sp[1]), fmaxf(sp[2], sp[3]));
        M[rt] = mm;
        float s = 0.f;
        #pragma unroll
        for (int e = 0; e < 3; ++e)
          #pragma unroll
          for (int ct = 0; ct < 4; ++ct)
            #pragma unroll
            for (int reg = 0; reg < 4; ++reg) {
                float p = __expf(acc[e][ct][rt][reg] - mm);
                acc[e][ct][rt][reg] = p;
                s += p;
            }
        s += __shfl_xor(s, 16);
        s += __shfl_xor(s, 32);
        if (g4 == 0) ssum[(rt*16 + a)*4 + w] = s;
    }
    __syncthreads();
    #pragma unroll
    for (int rt = 0; rt < 2; ++rt) {
        const float* sp = ssum + (rt*16 + a)*4;
        INV[rt] = 1.0f / (sp[0] + sp[1] + sp[2] + sp[3]);
    }

    // ---- scale to probs + attention store (b128 nontemporal) ----
    #pragma unroll
    for (int rt = 0; rt < 2; ++rt) {
        float* ab = attng + (((size_t)bb * SEQ + row0 + rt*16 + a) * NH + hh) * 768
                          + w*64 + g4*4;
        #pragma unroll
        for (int e = 0; e < 3; ++e)
          #pragma unroll
          for (int ct = 0; ct < 4; ++ct) {
            f32x4 p = acc[e][ct][rt] * INV[rt];
            acc[e][ct][rt] = p;
            __builtin_nontemporal_store(p, (f32x4*)(ab + e*256 + ct*16));
          }
    }

    // ---- PV: O^T = V^T * P^T (V^T frags from global, P^T via wave-private LDS)
    f32x4 acc2[4][2];
    #pragma unroll
    for (int dt = 0; dt < 4; ++dt)
      #pragma unroll
      for (int rt = 0; rt < 2; ++rt)
        acc2[dt][rt] = (f32x4){0.f, 0.f, 0.f, 0.f};

    #pragma unroll
    for (int e = 0; e < 3; ++e) {
        const int cs = cc + e - 1;
        if ((unsigned)cs < NC) {
            // stage P bf16 [row=rt*16+a][key=ct*16+g4*4+reg], stride 72 (b64 writes)
            #pragma unroll
            for (int rt = 0; rt < 2; ++rt)
              #pragma unroll
              for (int ct = 0; ct < 4; ++ct) {
                f32x4 p = acc[e][ct][rt];
                bf16x4 pk;
                #pragma unroll
                for (int reg = 0; reg < 4; ++reg) pk[reg] = (short)bf16_rne(p[reg]);
                *(bf16x4*)(pw + (rt*16 + a)*72 + ct*16 + g4*4) = pk;
              }
            // fragments + MFMA (wave-private: no barrier needed)
            #pragma unroll
            for (int ks = 0; ks < 2; ++ks) {
                bf16x8 pb[2], va[4];
                #pragma unroll
                for (int rt = 0; rt < 2; ++rt)
                    pb[rt] = *(const bf16x8*)(pw + (rt*16 + a)*72 + ks*32 + g4*8);
                #pragma unroll
                for (int dt = 0; dt < 4; ++dt)
                    va[dt] = *(const bf16x8*)(vtp
                        + (((size_t)bb * NH + hh) * DM + dt*16 + a) * SEQ
                        + cs*WIN + w*64 + ks*32 + g4*8);
                #pragma unroll
                for (int dt = 0; dt < 4; ++dt)
                  #pragma unroll
                  for (int rt = 0; rt < 2; ++rt)
                    acc2[dt][rt] = __builtin_amdgcn_mfma_f32_16x16x32_bf16(va[dt], pb[rt], acc2[dt][rt], 0, 0, 0);
            }
        }
    }

    // ---- cross-wave reduce + output ----
    __syncthreads();   // all waves done reading pw before csc overlays it
    #pragma unroll
    for (int dt = 0; dt < 4; ++dt)
      #pragma unroll
      for (int rt = 0; rt < 2; ++rt)
        *(f32x4*)&csc[w*2176 + (rt*16 + a)*68 + dt*16 + g4*4] = acc2[dt][rt];
    __syncthreads();
    #pragma unroll
    for (int r = 0; r < 8; ++r) {
        const int row = w*8 + r;
        float s = csc[          row*68 + lane] + csc[  2176 + row*68 + lane]
                + csc[2*2176 + row*68 + lane] + csc[3*2176 + row*68 + lane];
        __builtin_nontemporal_store(
            s, outg + (((size_t)bb * SEQ + row0 + row) * NH + hh) * DM + lane);
    }
}

// ============================== fallback (proven R4 kernel, unchanged) =======
__global__ __launch_bounds__(256, 2)
void wattn_mfma(const float* __restrict__ qg, const float* __restrict__ kg,
                const float* __restrict__ vg, float* __restrict__ outg,
                float* __restrict__ attng)
{
    __shared__ __align__(16) char lds[50176];
    const int t    = threadIdx.x;
    const int lane = t & 63;
    const int w    = t >> 6;
    const int a    = lane & 15;
    const int g4   = lane >> 4;

    unsigned short* vtw = (unsigned short*)(lds)         + w * 4096;
    unsigned short* plw = (unsigned short*)(lds + 32768) + w * 2048;
    float* smax = (float*)(lds + 49152);
    float* ssum = smax + 128;
    float* csc  = (float*)lds;

    int gid = blockIdx.x;
    gid = (gid & 7) * 512 + (gid >> 3);
    const int tile = gid & 7;  gid >>= 3;
    const int hh   = gid & 7;  gid >>= 3;
    const int cc   = gid & 31; gid >>= 5;
    const int bb   = gid;
    const int row0 = cc * WIN + tile * 32;

    bf16x8 qh[2][2], ql[2][2];
    #pragma unroll
    for (int rt = 0; rt < 2; ++rt)
      #pragma unroll
      for (int ks = 0; ks < 2; ++ks) {
        const float* qp = qg + (((size_t)bb * SEQ + row0 + rt*16 + a) * NH + hh) * DM
                             + ks*32 + g4*8;
        f32x4 t0 = *(const f32x4*)qp;
        f32x4 t1 = *(const f32x4*)(qp + 4);
        float f[8];
        #pragma unroll
        for (int i = 0; i < 4; ++i) { f[i] = t0[i]; f[4+i] = t1[i]; }
        #pragma unroll
        for (int i = 0; i < 8; ++i) {
            unsigned short h = bf16_rne(f[i]);
            qh[rt][ks][i] = (short)h;
            ql[rt][ks][i] = (short)bf16_rne(f[i] - bf16_f32(h));
        }
      }

    f32x4 acc[3][2][4];
    #pragma unroll
    for (int e = 0; e < 3; ++e)
      #pragma unroll
      for (int rt = 0; rt < 2; ++rt)
        #pragma unroll
        for (int ct = 0; ct < 4; ++ct)
            acc[e][rt][ct] = (f32x4){0.f, 0.f, 0.f, 0.f};

    #pragma unroll
    for (int e = 0; e < 3; ++e) {
        const int cs = cc + e - 1;
        if ((unsigned)cs < NC) {
            #pragma unroll
            for (int ct = 0; ct < 4; ++ct) {
                const float* kp = kg + (((size_t)bb * SEQ + cs*WIN + w*64 + ct*16 + a) * NH + hh) * DM;
                #pragma unroll
                for (int ks = 0; ks < 2; ++ks) {
                    f32x4 t0 = *(const f32x4*)(kp + ks*32 + g4*8);
                    f32x4 t1 = *(const f32x4*)(kp + ks*32 + g4*8 + 4);
                    float f[8];
                    #pragma unroll
                    for (int i = 0; i < 4; ++i) { f[i] = t0[i]; f[4+i] = t1[i]; }
                    bf16x8 kh, kl;
                    #pragma unroll
                    for (int i = 0; i < 8; ++i) {
                        unsigned short h = bf16_rne(f[i]);
                        kh[i] = (short)h;
                        kl[i] = (short)bf16_rne(f[i] - bf16_f32(h));
                    }
                    #pragma unroll
                    for (int rt = 0; rt < 2; ++rt) {
                        acc[e][rt][ct] = __builtin_amdgcn_mfma_f32_16x16x32_bf16(qh[rt][ks], kh, acc[e][rt][ct], 0, 0, 0);
                        acc[e][rt][ct] = __builtin_amdgcn_mfma_f32_16x16x32_bf16(qh[rt][ks], kl, acc[e][rt][ct], 0, 0, 0);
                        acc[e][rt][ct] = __builtin_amdgcn_mfma_f32_16x16x32_bf16(ql[rt][ks], kh, acc[e][rt][ct], 0, 0, 0);
                    }
                }
            }
        }
    }

    float M[2][4], INV[2][4];
    #pragma unroll
    for (int rt = 0; rt < 2; ++rt)
      #pragma unroll
      for (int reg = 0; reg < 4; ++reg) {
        float mm = -3.4e38f;
        #pragma unroll
        for (int e = 0; e < 3; ++e)
          #pragma unroll
          for (int ct = 0; ct < 4; ++ct)
            mm = fmaxf(mm, acc[e][rt][ct][reg]);
        mm = fmaxf(mm, __shfl_xor(mm, 1));
        mm = fmaxf(mm, __shfl_xor(mm, 2));
        mm = fmaxf(mm, __shfl_xor(mm, 4));
        mm = fmaxf(mm, __shfl_xor(mm, 8));
        if (a == 0) smax[(rt*16 + g4*4 + reg)*4 + w] = mm;
      }
    __syncthreads();
    #pragma unroll
    for (int rt = 0; rt < 2; ++rt)
      #pragma unroll
      for (int reg = 0; reg < 4; ++reg) {
        const float* sp = smax + (rt*16 + g4*4 + reg)*4;
        float mm = fmaxf(fmaxf(sp[0], sp[1]), fmaxf(sp[2], sp[3]));
        M[rt][reg] = mm;
        float s = 0.f;
        #pragma unroll
        for (int e = 0; e < 3; ++e)
          #pragma unroll
          for (int ct = 0; ct < 4; ++ct) {
            float p = __expf(acc[e][rt][ct][reg] - mm);
            acc[e][rt][ct][reg] = p;
            s += p;
          }
        s += __shfl_xor(s, 1);
        s += __shfl_xor(s, 2);
        s += __shfl_xor(s, 4);
        s += __shfl_xor(s, 8);
        if (a == 0) ssum[(rt*16 + g4*4 + reg)*4 + w] = s;
      }
    __syncthreads();
    #pragma unroll
    for (int rt = 0; rt < 2; ++rt)
      #pragma unroll
      for (int reg = 0; reg < 4; ++reg) {
        const float* sp = ssum + (rt*16 + g4*4 + reg)*4;
        INV[rt][reg] = 1.0f / (sp[0] + sp[1] + sp[2] + sp[3]);
      }

    #pragma unroll
    for (int rt = 0; rt < 2; ++rt)
      #pragma unroll
      for (int reg = 0; reg < 4; ++reg) {
        const float iv = INV[rt][reg];
        float* ab = attng + (((size_t)bb * SEQ + row0 + rt*16 + g4*4 + reg) * NH + hh) * 768
                          + w*64 + a;
        #pragma unroll
        for (int e = 0; e < 3; ++e)
          #pragma unroll
          for (int ct = 0; ct < 4; ++ct) {
            float p = acc[e][rt][ct][reg] * iv;
            acc[e][rt][ct][reg] = p;
            __builtin_nontemporal_store(p, ab + e*256 + ct*16);
          }
      }

    f32x4 acc2[2][4];
    #pragma unroll
    for (int rt = 0; rt < 2; ++rt)
      #pragma unroll
      for (int dt = 0; dt < 4; ++dt)
        acc2[rt][dt] = (f32x4){0.f, 0.f, 0.f, 0.f};

    #pragma unroll
    for (int e = 0; e < 3; ++e) {
        const int cs = cc + e - 1;
        if ((unsigned)cs < NC) {
            __syncthreads();
            #pragma unroll
            for (int i = 0; i < 16; ++i) {
                const int kk = i*4 + g4;
                const float* vp = vg + (((size_t)bb * SEQ + cs*WIN + w*64 + kk) * NH + hh) * DM
                                     + a*4;
                f32x4 v4 = *(const f32x4*)vp;
                #pragma unroll
                for (int j = 0; j < 4; ++j) {
                    const int d = a*4 + j;
                    vtw[(d>>4)*1024 + (kk>>3)*128 + (d&15)*8 + (kk&7)] = bf16_rne(v4[j]);
                }
            }
            #pragma unroll
            for (int rt = 0; rt < 2; ++rt)
              #pragma unroll
              for (int reg = 0; reg < 4; ++reg) {
                const int prow = rt*16 + g4*4 + reg;
                #pragma unroll
                for (int ct = 0; ct < 4; ++ct) {
                    const int key = ct*16 + a;
                    plw[prow*64 + (((key>>3) ^ (prow&7)) << 3) + (key&7)] =
                        bf16_rne(acc[e][rt][ct][reg]);
                }
              }
            __syncthreads();
            #pragma unroll
            for (int ks = 0; ks < 2; ++ks) {
                bf16x8 pa[2], vb[4];
                #pragma unroll
                for (int rt = 0; rt < 2; ++rt) {
                    const int prow = rt*16 + a;
                    pa[rt] = *(const bf16x8*)(plw + prow*64 + ((((ks<<2) + g4) ^ (prow&7)) << 3));
                }
                #pragma unroll
                for (int dt = 0; dt < 4; ++dt)
                    vb[dt] = *(const bf16x8*)(vtw + dt*1024 + ((ks<<2) + g4)*128 + a*8);
                #pragma unroll
                for (int rt = 0; rt < 2; ++rt)
                  #pragma unroll
                  for (int dt = 0; dt < 4; ++dt)
                    acc2[rt][dt] = __builtin_amdgcn_mfma_f32_16x16x32_bf16(pa[rt], vb[dt], acc2[rt][dt], 0, 0, 0);
            }
        }
    }

    __syncthreads();
    #pragma unroll
    for (int rt = 0; rt < 2; ++rt)
      #pragma unroll
      for (int dt = 0; dt < 4; ++dt)
        #pragma unroll
        for (int reg = 0; reg < 4; ++reg)
          csc[w*2176 + (rt*16 + g4*4 + reg)*68 + dt*16 + a] = acc2[rt][dt][reg];
    __syncthreads();
    #pragma unroll
    for (int r = 0; r < 8; ++r) {
        const int row = w*8 + r;
        float s = csc[          row*68 + lane] + csc[  2176 + row*68 + lane]
                + csc[2*2176 + row*68 + lane] + csc[3*2176 + row*68 + lane];
        __builtin_nontemporal_store(
            s, outg + (((size_t)bb * SEQ + row0 + row) * NH + hh) * DM + lane);
    }
}

extern "C" void kernel_launch(void* const* d_in, const int* in_sizes, int n_in,
                              void* d_out, int out_size, void* d_ws, size_t ws_size,
                              hipStream_t stream) {
    const float* q = (const float*)d_in[0];
    const float* k = (const float*)d_in[1];
    const float* v = (const float*)d_in[2];

    float* out  = (float*)d_out;
    float* attn = (float*)d_out + (size_t)2 * SEQ * NH * DM;

    const size_t NELEM = (size_t)2 * SEQ * NH * DM;   // 8388608
    const size_t NEED  = 3 * NELEM * sizeof(u16);     // 50331648 B

    if (ws_size >= NEED) {
        u16* khp = (u16*)d_ws;
        u16* klp = khp + NELEM;
        u16* vtp = klp + NELEM;
        wattn_prep<<<dim3(6144), dim3(256), 0, stream>>>(k, v, khp, klp, vtp);
        wattn_mfma2<<<dim3(4096), dim3(256), 0, stream>>>(q, khp, klp, vtp, out, attn);
    } else {
        wattn_mfma<<<dim3(4096), dim3(256), 0, stream>>>(q, k, v, out, attn);
    }
}